// Round 2
// baseline (207.613 us; speedup 1.0000x reference)
//
#include <hip/hip_runtime.h>

// Problem constants (from reference): B=128, TX=512, D_A=512.
// KEY INSIGHT: softmax over the size-1 last axis makes alphas == 1.0 exactly,
// so the output is simply context[b,0,d] = sum_t a[b,t,d].
// Everything else (s_prev, W1/b1 tanh MLP, W2/b2 relu) is dead code.
constexpr int B  = 128;
constexpr int TX = 512;
constexpr int DA = 512;
constexpr int SPLIT = 16;            // t-axis split per batch
constexpr int ROWS  = TX / SPLIT;    // 32 rows per block

__global__ __launch_bounds__(256) void zero_out_kernel(float* __restrict__ out, int n) {
    int i = blockIdx.x * 256 + threadIdx.x;
    if (i < n) out[i] = 0.f;
}

// Grid: B*SPLIT = 2048 blocks, 256 threads (8192 waves; full occupancy).
// Each block: batch b = bid/SPLIT, row slice s = bid%SPLIT (32 contiguous rows = 64 KB).
// Threads 0..127 own float4 column `lane` on even rows of the slice,
// threads 128..255 the same columns on odd rows; halves combined via LDS,
// then one set of 512 float atomicAdds per block into out[b,:].
__global__ __launch_bounds__(256) void colsum_kernel(const float* __restrict__ a,
                                                     float* __restrict__ out) {
    const int bid  = blockIdx.x;
    const int b    = bid >> 4;            // / SPLIT
    const int s    = bid & (SPLIT - 1);
    const int tid  = threadIdx.x;
    const int half = tid >> 7;            // 0 or 1
    const int lane = tid & 127;           // float4 column index (128 * 16B = 512 floats/row)

    const float4* ap = reinterpret_cast<const float4*>(a)
                     + (size_t)b * (TX * DA / 4) + lane;

    float4 acc = make_float4(0.f, 0.f, 0.f, 0.f);
    const int tbeg = s * ROWS + half;
    const int tend = s * ROWS + ROWS;
    #pragma unroll
    for (int t = tbeg; t < tend; t += 2) {  // 16 iterations, stride 2 rows
        float4 v = ap[(size_t)t * (DA / 4)];
        acc.x += v.x; acc.y += v.y; acc.z += v.z; acc.w += v.w;
    }

    __shared__ float4 sh[128];
    if (half) sh[lane] = acc;
    __syncthreads();
    if (!half) {
        float4 o = sh[lane];
        acc.x += o.x; acc.y += o.y; acc.z += o.z; acc.w += o.w;
        float* op = out + (size_t)b * DA + lane * 4;
        atomicAdd(op + 0, acc.x);
        atomicAdd(op + 1, acc.y);
        atomicAdd(op + 2, acc.z);
        atomicAdd(op + 3, acc.w);
    }
}

extern "C" void kernel_launch(void* const* d_in, const int* in_sizes, int n_in,
                              void* d_out, int out_size, void* d_ws, size_t ws_size,
                              hipStream_t stream) {
    const float* a = (const float*)d_in[0];   // [B, TX, DA] f32
    // d_in[1..5] = s_prev, W1, b1, W2, b2 — mathematically dead (softmax over size-1 axis).
    float* out = (float*)d_out;               // [B, 1, DA] f32 = 65536 floats

    // d_out is re-poisoned to 0xAA before every timed launch: clear it first.
    zero_out_kernel<<<(out_size + 255) / 256, 256, 0, stream>>>(out, out_size);
    colsum_kernel<<<B * SPLIT, 256, 0, stream>>>(a, out);
}

// Round 3
// 201.389 us; speedup vs baseline: 1.0309x; 1.0309x over previous
//
#include <hip/hip_runtime.h>

// Problem constants (from reference): B=128, TX=512, D_A=512.
// KEY INSIGHT: softmax over the size-1 last axis makes alphas == 1.0 exactly,
// so the output is simply context[b,0,d] = sum_t a[b,t,d].
// Everything else (s_prev, W1/b1 tanh MLP, W2/b2 relu) is dead code.
constexpr int B  = 128;
constexpr int TX = 512;
constexpr int DA = 512;
constexpr int SPLIT = 16;            // t-axis split per batch
constexpr int ROWS  = TX / SPLIT;    // 32 rows per block

// Stage 1: grid B*SPLIT = 2048 blocks, 256 threads (32 waves/CU capacity).
// Each block streams 32 contiguous rows (64 KB) of one batch and writes its
// 512-float partial sum to ws[bid] — no atomics, no pre-zeroing.
__global__ __launch_bounds__(256) void colsum_partial(const float* __restrict__ a,
                                                      float4* __restrict__ partial) {
    const int bid  = blockIdx.x;
    const int b    = bid >> 4;            // / SPLIT
    const int s    = bid & (SPLIT - 1);
    const int tid  = threadIdx.x;
    const int half = tid >> 7;            // 0 or 1
    const int lane = tid & 127;           // float4 column (128 * 16B = 512 floats/row)

    const float4* ap = reinterpret_cast<const float4*>(a)
                     + (size_t)b * (TX * DA / 4) + lane;

    float4 acc = make_float4(0.f, 0.f, 0.f, 0.f);
    const int tbeg = s * ROWS + half;
    const int tend = s * ROWS + ROWS;
    #pragma unroll
    for (int t = tbeg; t < tend; t += 2) {  // 16 iterations, stride 2 rows
        float4 v = ap[(size_t)t * (DA / 4)];
        acc.x += v.x; acc.y += v.y; acc.z += v.z; acc.w += v.w;
    }

    __shared__ float4 sh[128];
    if (half) sh[lane] = acc;
    __syncthreads();
    if (!half) {
        float4 o = sh[lane];
        acc.x += o.x; acc.y += o.y; acc.z += o.z; acc.w += o.w;
        partial[(size_t)bid * 128 + lane] = acc;   // [2048][128] float4 = 4 MB in ws
    }
}

// Stage 2: 64 blocks x 256 threads = 16384 threads, one float4 of out each.
// out[b][lane] = sum_{s=0..15} partial[b*16+s][lane]. Reads 4 MB (L2-hot),
// writes 256 KB, fully overwrites d_out (poisoned 0xAA) — no zero kernel.
__global__ __launch_bounds__(256) void colsum_reduce(const float4* __restrict__ partial,
                                                     float4* __restrict__ out) {
    const int i    = blockIdx.x * 256 + threadIdx.x;   // 0..16383
    const int b    = i >> 7;              // batch
    const int lane = i & 127;             // float4 column

    const float4* pp = partial + (size_t)b * SPLIT * 128 + lane;
    float4 acc = make_float4(0.f, 0.f, 0.f, 0.f);
    #pragma unroll
    for (int s = 0; s < SPLIT; ++s) {
        float4 v = pp[(size_t)s * 128];
        acc.x += v.x; acc.y += v.y; acc.z += v.z; acc.w += v.w;
    }
    out[i] = acc;
}

extern "C" void kernel_launch(void* const* d_in, const int* in_sizes, int n_in,
                              void* d_out, int out_size, void* d_ws, size_t ws_size,
                              hipStream_t stream) {
    const float* a = (const float*)d_in[0];   // [B, TX, DA] f32
    // d_in[1..5] = s_prev, W1, b1, W2, b2 — mathematically dead (softmax over size-1 axis).
    float4* partial = (float4*)d_ws;          // 4 MB of the workspace
    float4* out     = (float4*)d_out;         // [B, 1, DA] f32 = 16384 float4

    colsum_partial<<<B * SPLIT, 256, 0, stream>>>(a, partial);
    colsum_reduce<<<(B * DA / 4) / 256, 256, 0, stream>>>(partial, out);
}